// Round 6
// baseline (14.353 us; speedup 1.0000x reference)
//
#include <hip/hip_runtime.h>
#include <math.h>

#define FXc 300.0f
#define FYc 300.0f
#define CXc 128.0f
#define CYc 128.0f
#define BGc 1.0f
#define EPS2Dc 0.3f
#define NEARc 0.01f
#define C0c 0.28209479177387814f

#define MAXP 512   // max points (N_PTS == 512); also bitonic network size
#define SEG  4     // depth segments composited in parallel

// Fully fused, depth-parallel: each block owns a 16x16 tile, 1024 threads.
// Threads 0..511 preprocess one point each and cull vs tile. Survivor order
// comes from a hybrid bitonic sort over packed (z_bits<<32|idx) u64 keys held
// in REGISTERS: strides<=32 via __shfl_xor (race-free), strides>=64 via LDS
// with full barriers on both sides. idx tiebreak == stable argsort.
// Params scatter from registers into the depth-sorted LDS table, then all
// 16 waves composite: 4 depth segments x 256 pixels, folded associatively.
__global__ void __launch_bounds__(1024)
gs_fused(const float* __restrict__ cam,
         const float* __restrict__ means,
         const float* __restrict__ quats,
         const float* __restrict__ scales,
         const float* __restrict__ opacs,
         const float* __restrict__ sh0,
         const int* __restrict__ img_w_p,
         float* __restrict__ out,
         int n, int npix)
{
    __shared__ float4 spts[MAXP][3];              // depth-sorted survivor params
    __shared__ unsigned long long keys[MAXP];     // staging for cross-wave stages
    __shared__ int  srank[MAXP];                  // orig idx -> sorted rank
    __shared__ int  scnt[MAXP / 64];
    __shared__ int  sK;
    __shared__ float4 comb[SEG - 1][256];         // per-segment partials (r,g,b,T)

    const int lt   = threadIdx.x;
    const int wave = lt >> 6;

    const int W = *img_w_p;
    const int tiles_x = W >> 4;                   // assumes W % 16 == 0
    const int tx = (blockIdx.x % tiles_x) << 4;
    const int ty = (blockIdx.x / tiles_x) << 4;
    const float tx0 = (float)tx + 0.5f, tx1 = (float)tx + 15.5f;
    const float ty0 = (float)ty + 0.5f, ty1 = (float)ty + 15.5f;

    // ---------------- preprocess: one point per thread (lt < 512) -------------
    float pmx = 0.f, pmy = 0.f, pA_ = 0.f, pB_ = 0.f, pC_ = 0.f;
    float pop = 0.f, pcr = 0.f, pcg = 0.f, pcb = 0.f, pz = 0.f;
    bool phit = false;

    if (lt < MAXP) {
        // camera: c2w = [M|b]; viewmat = inv(c2w) with rows 1,2 negated
        const float a00 = cam[0], a01 = cam[1], a02 = cam[2],  b0 = cam[3];
        const float a10 = cam[4], a11 = cam[5], a12 = cam[6],  b1 = cam[7];
        const float a20 = cam[8], a21 = cam[9], a22 = cam[10], b2 = cam[11];
        const float det3 = a00*(a11*a22 - a12*a21) - a01*(a10*a22 - a12*a20) + a02*(a10*a21 - a11*a20);
        const float id = 1.0f / det3;
        const float i00 = (a11*a22 - a12*a21)*id, i01 = (a02*a21 - a01*a22)*id, i02 = (a01*a12 - a02*a11)*id;
        const float i10 = (a12*a20 - a10*a22)*id, i11 = (a00*a22 - a02*a20)*id, i12 = (a02*a10 - a00*a12)*id;
        const float i20 = (a10*a21 - a11*a20)*id, i21 = (a01*a20 - a00*a21)*id, i22 = (a00*a11 - a01*a10)*id;
        const float R00 = i00,  R01 = i01,  R02 = i02;
        const float R10 = -i10, R11 = -i11, R12 = -i12;
        const float R20 = -i20, R21 = -i21, R22 = -i22;
        const float t0 = -(i00*b0 + i01*b1 + i02*b2);
        const float t1 = (i10*b0 + i11*b1 + i12*b2);
        const float t2 = (i20*b0 + i21*b1 + i22*b2);
        const float limx_e = 1.3f * (0.5f * (float)W / FXc);
        const float limy_e = limx_e;

        const int p = lt;
        bool hit = false;
        if (p < n) {
            const float m0 = means[3*p], m1 = means[3*p+1], m2 = means[3*p+2];
            const float px_ = R00*m0 + R01*m1 + R02*m2 + t0;
            const float py_ = R10*m0 + R11*m1 + R12*m2 + t1;
            const float pz_ = R20*m0 + R21*m1 + R22*m2 + t2;

            bool valid = pz_ > NEARc;
            const float zs = valid ? pz_ : 1.0f;
            const float rz = 1.0f / zs;

            float qw = quats[4*p], qx = quats[4*p+1], qy = quats[4*p+2], qz = quats[4*p+3];
            const float qn = rsqrtf(qw*qw + qx*qx + qy*qy + qz*qz);
            qw *= qn; qx *= qn; qy *= qn; qz *= qn;
            const float Rq00 = 1.f - 2.f*(qy*qy + qz*qz), Rq01 = 2.f*(qx*qy - qw*qz), Rq02 = 2.f*(qx*qz + qw*qy);
            const float Rq10 = 2.f*(qx*qy + qw*qz), Rq11 = 1.f - 2.f*(qx*qx + qz*qz), Rq12 = 2.f*(qy*qz - qw*qx);
            const float Rq20 = 2.f*(qx*qz - qw*qy), Rq21 = 2.f*(qy*qz + qw*qx), Rq22 = 1.f - 2.f*(qx*qx + qy*qy);

            const float e0 = __expf(scales[3*p]), e1 = __expf(scales[3*p+1]), e2 = __expf(scales[3*p+2]);
            const float M00 = Rq00*e0, M01 = Rq01*e1, M02 = Rq02*e2;
            const float M10 = Rq10*e0, M11 = Rq11*e1, M12 = Rq12*e2;
            const float M20 = Rq20*e0, M21 = Rq21*e1, M22 = Rq22*e2;

            const float S00 = M00*M00 + M01*M01 + M02*M02;
            const float S01 = M00*M10 + M01*M11 + M02*M12;
            const float S02 = M00*M20 + M01*M21 + M02*M22;
            const float S11 = M10*M10 + M11*M11 + M12*M12;
            const float S12 = M10*M20 + M11*M21 + M12*M22;
            const float S22 = M20*M20 + M21*M21 + M22*M22;

            const float U00 = R00*S00 + R01*S01 + R02*S02;
            const float U01 = R00*S01 + R01*S11 + R02*S12;
            const float U02 = R00*S02 + R01*S12 + R02*S22;
            const float U10 = R10*S00 + R11*S01 + R12*S02;
            const float U11 = R10*S01 + R11*S11 + R12*S12;
            const float U12 = R10*S02 + R11*S12 + R12*S22;
            const float U20 = R20*S00 + R21*S01 + R22*S02;
            const float U21 = R20*S01 + R21*S11 + R22*S12;
            const float U22 = R20*S02 + R21*S12 + R22*S22;

            const float C00 = U00*R00 + U01*R01 + U02*R02;
            const float C01 = U00*R10 + U01*R11 + U02*R12;
            const float C02 = U00*R20 + U01*R21 + U02*R22;
            const float C11 = U10*R10 + U11*R11 + U12*R12;
            const float C12 = U10*R20 + U11*R21 + U12*R22;
            const float C22 = U20*R20 + U21*R21 + U22*R22;

            const float txc = zs * fminf(fmaxf(px_*rz, -limx_e), limx_e);
            const float tyc = zs * fminf(fmaxf(py_*rz, -limy_e), limy_e);
            const float ja0 = FXc * rz;
            const float ja2 = -FXc * txc * rz * rz;
            const float jb1 = FYc * rz;
            const float jb2 = -FYc * tyc * rz * rz;

            const float c2d00 = ja0*ja0*C00 + 2.f*ja0*ja2*C02 + ja2*ja2*C22 + EPS2Dc;
            const float c2d01 = ja0*jb1*C01 + ja0*jb2*C02 + ja2*jb1*C12 + ja2*jb2*C22;
            const float c2d11 = jb1*jb1*C11 + 2.f*jb1*jb2*C12 + jb2*jb2*C22 + EPS2Dc;

            const float det2 = c2d00*c2d11 - c2d01*c2d01;
            valid = valid && (det2 > 1e-12f);
            const float rdet = 1.0f / (valid ? det2 : 1.0f);
            pA_ = c2d11 * rdet;
            pB_ = -c2d01 * rdet;
            pC_ = c2d00 * rdet;

            pmx = FXc * px_ * rz + CXc;
            pmy = FYc * py_ * rz + CYc;

            pcr = fmaxf(C0c * sh0[3*p+0] + 0.5f, 0.0f);
            pcg = fmaxf(C0c * sh0[3*p+1] + 0.5f, 0.0f);
            pcb = fmaxf(C0c * sh0[3*p+2] + 0.5f, 0.0f);
            pop = 1.0f / (1.0f + __expf(-opacs[p]));
            pz  = pz_;

            const float op255 = pop * 255.0f;
            if (valid && op255 >= 1.0f) {
                const float s = __logf(op255);
                const float dxm = sqrtf(2.0f * s * c2d00) * 1.0001f + 0.01f;
                const float dym = sqrtf(2.0f * s * c2d11) * 1.0001f + 0.01f;
                hit = (pmx - dxm <= tx1) && (pmx + dxm >= tx0) &&
                      (pmy - dym <= ty1) && (pmy + dym >= ty0);
            }
        }
        phit = hit;
        const unsigned long long m = __ballot(hit);
        if ((lt & 63) == 0) scnt[wave] = __popcll(m);
    }

    // pack sort key: z>NEAR>0 for all hits -> float bits are order-monotone;
    // low 32 bits = original index (stable tiebreak). Culled/extra -> ~0.
    unsigned long long key = ~0ull;
    if (phit) key = ((unsigned long long)__float_as_uint(pz) << 32) | (unsigned)lt;

    __syncthreads();
    if (lt == 0) {
        int acc = 0;
        #pragma unroll
        for (int c = 0; c < MAXP/64; ++c) acc += scnt[c];
        sK = acc;
    }

    // ------------- hybrid bitonic sort of 512 u64 keys (ascending) ------------
    // key lives in a register. strides<=32: __shfl_xor compare-exchange.
    // strides>=64: stage through LDS with barriers on both sides.
    {
        const bool active = (lt < MAXP);
        // sizes 2..64: all strides in-wave
        for (int size = 2; size <= 64; size <<= 1) {
            const bool dir = ((lt & size) == 0);
            for (int stride = size >> 1; stride > 0; stride >>= 1) {
                if (active) {
                    const unsigned long long b = __shfl_xor(key, stride, 64);
                    const bool lower = ((lt & stride) == 0);
                    const bool takeMin = (lower == dir);
                    key = takeMin ? (key < b ? key : b) : (key > b ? key : b);
                }
            }
        }
        // sizes 128..512: cross-wave strides via LDS, then in-wave tail
        for (int size = 128; size <= MAXP; size <<= 1) {
            const bool dir = ((lt & size) == 0);
            for (int stride = size >> 1; stride >= 64; stride >>= 1) {
                __syncthreads();                 // WAR: prior reads done
                if (active) keys[lt] = key;
                __syncthreads();                 // RAW: all writes visible
                if (active) {
                    const unsigned long long b = keys[lt ^ stride];
                    const bool lower = ((lt & stride) == 0);
                    const bool takeMin = (lower == dir);
                    key = takeMin ? (key < b ? key : b) : (key > b ? key : b);
                }
            }
            for (int stride = 32; stride > 0; stride >>= 1) {
                if (active) {
                    const unsigned long long b = __shfl_xor(key, stride, 64);
                    const bool lower = ((lt & stride) == 0);
                    const bool takeMin = (lower == dir);
                    key = takeMin ? (key < b ? key : b) : (key > b ? key : b);
                }
            }
        }
    }

    // thread lt now holds the rank-lt key: build orig idx -> rank map
    if (lt < MAXP && key != ~0ull) srank[(int)(key & 0xffffffffu)] = lt;
    __syncthreads();

    // scatter params from registers into depth-sorted LDS table
    if (phit) {
        const int r = srank[lt];
        spts[r][0] = make_float4(pmx, pmy, pA_, pB_);
        spts[r][1] = make_float4(pC_, pop, pcr, pcg);
        spts[r][2] = make_float4(pcb, 0.f, 0.f, 0.f);
    }
    __syncthreads();
    const int k = sK;

    // ------------- depth-parallel compositing: SEG segments x 256 px ----------
    const int s   = lt >> 8;          // segment 0..3 (front..back)
    const int pix = lt & 255;
    const int col = tx + (pix & 15);
    const int row = ty + (pix >> 4);
    const float px = (float)col + 0.5f;
    const float py = (float)row + 0.5f;

    const int beg = (k * s) >> 2;             // SEG == 4
    const int end = (k * (s + 1)) >> 2;

    float T = 1.0f, r_ = 0.f, g_ = 0.f, b_ = 0.f;
    for (int base = beg; base < end; base += 16) {
        const int lim = (base + 16 < end) ? base + 16 : end;
        #pragma unroll 4
        for (int i = base; i < lim; ++i) {
            const float4 a4 = spts[i][0];        // mx, my, cA, cB
            const float4 b4 = spts[i][1];        // cC, op, cr, cg
            const float  cbv = spts[i][2].x;     // cb

            const float dx = px - a4.x;
            const float dy = py - a4.y;
            const float sigma = 0.5f * (a4.z*dx*dx + b4.x*dy*dy) + a4.w*dx*dy;
            float al = b4.y * __expf(-sigma);
            al = fminf(al, 0.999f);
            const bool keep = (sigma >= 0.0f) && (al >= (1.0f/255.0f));
            al = keep ? al : 0.0f;

            const float w = T * al;
            r_ += w * b4.z;
            g_ += w * b4.w;
            b_ += w * cbv;
            T = __builtin_fmaf(-al, T, T);       // T *= (1 - al), 1 slot
        }
        if (!__any(T > 1e-4f)) break;    // segment tail scaled by <=1: err <= 1e-4
    }

    if (s > 0) comb[s - 1][pix] = make_float4(r_, g_, b_, T);
    __syncthreads();

    if (s == 0) {
        const float4 f1 = comb[0][pix];
        const float4 f2 = comb[1][pix];
        const float4 f3 = comb[2][pix];
        // fold back-to-front: C = C0 + T0*(C1 + T1*(C2 + T2*C3)); T = prod
        float rr = r_ + T * (f1.x + f1.w * (f2.x + f2.w * f3.x));
        float gg = g_ + T * (f1.y + f1.w * (f2.y + f2.w * f3.y));
        float bb = b_ + T * (f1.z + f1.w * (f2.z + f2.w * f3.z));
        const float Tt = T * f1.w * f2.w * f3.w;
        rr += Tt * BGc; gg += Tt * BGc; bb += Tt * BGc;

        const int opix = row * W + col;
        if (opix < npix) {
            out[3*opix + 0] = rr;
            out[3*opix + 1] = gg;
            out[3*opix + 2] = bb;
            out[3*npix + opix] = 1.0f - Tt;
        }
    }
}

extern "C" void kernel_launch(void* const* d_in, const int* in_sizes, int n_in,
                              void* d_out, int out_size, void* d_ws, size_t ws_size,
                              hipStream_t stream) {
    const float* cam    = (const float*)d_in[0];
    const float* means  = (const float*)d_in[1];
    const float* quats  = (const float*)d_in[2];
    const float* scales = (const float*)d_in[3];
    const float* opacs  = (const float*)d_in[4];
    const float* sh0    = (const float*)d_in[5];
    // d_in[6] = shN (unused by the reference render)
    const int* img_w = (const int*)d_in[8];

    const int n = in_sizes[4];            // N_PTS (== 512 for this problem)
    const int npix = out_size / 4;        // 3 color + 1 alpha per pixel

    const int blocks = npix / 256;        // one 16x16 tile per block
    gs_fused<<<blocks, 1024, 0, stream>>>(cam, means, quats, scales, opacs, sh0,
                                          img_w, (float*)d_out, n, npix);
}

// Round 7
// 10.355 us; speedup vs baseline: 1.3861x; 1.3861x over previous
//
#include <hip/hip_runtime.h>
#include <math.h>

#define FXc 300.0f
#define FYc 300.0f
#define CXc 128.0f
#define CYc 128.0f
#define BGc 1.0f
#define EPS2Dc 0.3f
#define NEARc 0.01f
#define C0c 0.28209479177387814f

#define MAXP 512   // max points (N_PTS == 512)
#define SEG  4     // depth segments composited in parallel

// Fully fused, depth-parallel: each block owns a 16x16 tile, 1024 threads.
// Threads 0..511 preprocess one point each; cull = EXACT min-sigma-over-tile
// test (removes only provably-zero contributors). Survivors ballot-compact,
// stable rank-sort by z (vectorized scan), scatter into depth-sorted LDS,
// then 16 waves composite: 4 depth segments x 256 pixels, folded associatively.
__global__ void __launch_bounds__(1024)
gs_fused(const float* __restrict__ cam,
         const float* __restrict__ means,
         const float* __restrict__ quats,
         const float* __restrict__ scales,
         const float* __restrict__ opacs,
         const float* __restrict__ sh0,
         const int* __restrict__ img_w_p,
         float* __restrict__ out,
         int n, int npix)
{
    __shared__ float4 spts[MAXP][3];              // depth-sorted survivor params
    __shared__ __align__(16) float zc[MAXP + 4];  // compacted survivor z (+INF pad)
    __shared__ int scnt[MAXP / 64];
    __shared__ int sbase[MAXP / 64 + 1];
    __shared__ float4 comb[SEG - 1][256];         // per-segment partials (r,g,b,T)

    const int lt   = threadIdx.x;
    const int wave = lt >> 6;

    const int W = *img_w_p;
    const int tiles_x = W >> 4;                   // assumes W % 16 == 0
    const int tx = (blockIdx.x % tiles_x) << 4;
    const int ty = (blockIdx.x / tiles_x) << 4;
    const float tx0 = (float)tx + 0.5f, tx1 = (float)tx + 15.5f;
    const float ty0 = (float)ty + 0.5f, ty1 = (float)ty + 15.5f;

    const int nchunks = (n + 63) >> 6;            // <= 8

    // ---------------- preprocess: one point per thread (lt < 512) -------------
    float pmx = 0.f, pmy = 0.f, pA_ = 0.f, pB_ = 0.f, pC_ = 0.f;
    float pop = 0.f, pcr = 0.f, pcg = 0.f, pcb = 0.f, pz = 0.f;
    unsigned long long mreg = 0ull;
    bool phit = false;

    if (lt < MAXP) {
        // camera: c2w = [M|b]; viewmat = inv(c2w) with rows 1,2 negated
        const float a00 = cam[0], a01 = cam[1], a02 = cam[2],  b0 = cam[3];
        const float a10 = cam[4], a11 = cam[5], a12 = cam[6],  b1 = cam[7];
        const float a20 = cam[8], a21 = cam[9], a22 = cam[10], b2 = cam[11];
        const float det3 = a00*(a11*a22 - a12*a21) - a01*(a10*a22 - a12*a20) + a02*(a10*a21 - a11*a20);
        const float id = 1.0f / det3;
        const float i00 = (a11*a22 - a12*a21)*id, i01 = (a02*a21 - a01*a22)*id, i02 = (a01*a12 - a02*a11)*id;
        const float i10 = (a12*a20 - a10*a22)*id, i11 = (a00*a22 - a02*a20)*id, i12 = (a02*a10 - a00*a12)*id;
        const float i20 = (a10*a21 - a11*a20)*id, i21 = (a01*a20 - a00*a21)*id, i22 = (a00*a11 - a01*a10)*id;
        const float R00 = i00,  R01 = i01,  R02 = i02;
        const float R10 = -i10, R11 = -i11, R12 = -i12;
        const float R20 = -i20, R21 = -i21, R22 = -i22;
        const float t0 = -(i00*b0 + i01*b1 + i02*b2);
        const float t1 = (i10*b0 + i11*b1 + i12*b2);
        const float t2 = (i20*b0 + i21*b1 + i22*b2);
        const float limx_e = 1.3f * (0.5f * (float)W / FXc);
        const float limy_e = limx_e;

        const int p = lt;
        bool hit = false;
        if (p < n) {
            const float m0 = means[3*p], m1 = means[3*p+1], m2 = means[3*p+2];
            const float px_ = R00*m0 + R01*m1 + R02*m2 + t0;
            const float py_ = R10*m0 + R11*m1 + R12*m2 + t1;
            const float pz_ = R20*m0 + R21*m1 + R22*m2 + t2;

            bool valid = pz_ > NEARc;
            const float zs = valid ? pz_ : 1.0f;
            const float rz = 1.0f / zs;

            float qw = quats[4*p], qx = quats[4*p+1], qy = quats[4*p+2], qz = quats[4*p+3];
            const float qn = rsqrtf(qw*qw + qx*qx + qy*qy + qz*qz);
            qw *= qn; qx *= qn; qy *= qn; qz *= qn;
            const float Rq00 = 1.f - 2.f*(qy*qy + qz*qz), Rq01 = 2.f*(qx*qy - qw*qz), Rq02 = 2.f*(qx*qz + qw*qy);
            const float Rq10 = 2.f*(qx*qy + qw*qz), Rq11 = 1.f - 2.f*(qx*qx + qz*qz), Rq12 = 2.f*(qy*qz - qw*qx);
            const float Rq20 = 2.f*(qx*qz - qw*qy), Rq21 = 2.f*(qy*qz + qw*qx), Rq22 = 1.f - 2.f*(qx*qx + qy*qy);

            const float e0 = __expf(scales[3*p]), e1 = __expf(scales[3*p+1]), e2 = __expf(scales[3*p+2]);
            const float M00 = Rq00*e0, M01 = Rq01*e1, M02 = Rq02*e2;
            const float M10 = Rq10*e0, M11 = Rq11*e1, M12 = Rq12*e2;
            const float M20 = Rq20*e0, M21 = Rq21*e1, M22 = Rq22*e2;

            const float S00 = M00*M00 + M01*M01 + M02*M02;
            const float S01 = M00*M10 + M01*M11 + M02*M12;
            const float S02 = M00*M20 + M01*M21 + M02*M22;
            const float S11 = M10*M10 + M11*M11 + M12*M12;
            const float S12 = M10*M20 + M11*M21 + M12*M22;
            const float S22 = M20*M20 + M21*M21 + M22*M22;

            const float U00 = R00*S00 + R01*S01 + R02*S02;
            const float U01 = R00*S01 + R01*S11 + R02*S12;
            const float U02 = R00*S02 + R01*S12 + R02*S22;
            const float U10 = R10*S00 + R11*S01 + R12*S02;
            const float U11 = R10*S01 + R11*S11 + R12*S12;
            const float U12 = R10*S02 + R11*S12 + R12*S22;
            const float U20 = R20*S00 + R21*S01 + R22*S02;
            const float U21 = R20*S01 + R21*S11 + R22*S12;
            const float U22 = R20*S02 + R21*S12 + R22*S22;

            const float C00 = U00*R00 + U01*R01 + U02*R02;
            const float C01 = U00*R10 + U01*R11 + U02*R12;
            const float C02 = U00*R20 + U01*R21 + U02*R22;
            const float C11 = U10*R10 + U11*R11 + U12*R12;
            const float C12 = U10*R20 + U11*R21 + U12*R22;
            const float C22 = U20*R20 + U21*R21 + U22*R22;

            const float txc = zs * fminf(fmaxf(px_*rz, -limx_e), limx_e);
            const float tyc = zs * fminf(fmaxf(py_*rz, -limy_e), limy_e);
            const float ja0 = FXc * rz;
            const float ja2 = -FXc * txc * rz * rz;
            const float jb1 = FYc * rz;
            const float jb2 = -FYc * tyc * rz * rz;

            const float c2d00 = ja0*ja0*C00 + 2.f*ja0*ja2*C02 + ja2*ja2*C22 + EPS2Dc;
            const float c2d01 = ja0*jb1*C01 + ja0*jb2*C02 + ja2*jb1*C12 + ja2*jb2*C22;
            const float c2d11 = jb1*jb1*C11 + 2.f*jb1*jb2*C12 + jb2*jb2*C22 + EPS2Dc;

            const float det2 = c2d00*c2d11 - c2d01*c2d01;
            valid = valid && (det2 > 1e-12f);
            const float rdet = 1.0f / (valid ? det2 : 1.0f);
            pA_ = c2d11 * rdet;             // conic a  (>0)
            pB_ = -c2d01 * rdet;            // conic b
            pC_ = c2d00 * rdet;             // conic c  (>0)

            pmx = FXc * px_ * rz + CXc;
            pmy = FYc * py_ * rz + CYc;

            pcr = fmaxf(C0c * sh0[3*p+0] + 0.5f, 0.0f);
            pcg = fmaxf(C0c * sh0[3*p+1] + 0.5f, 0.0f);
            pcb = fmaxf(C0c * sh0[3*p+2] + 0.5f, 0.0f);
            pop = 1.0f / (1.0f + __expf(-opacs[p]));
            pz  = pz_;

            // ---- EXACT cull: min over tile rect of sigma(d) = 0.5 a dx^2 +
            // 0.5 c dy^2 + b dx dy  vs  smax = log(255*op). PSD => global min
            // at center; if center outside rect, min is on one of 4 edges
            // (1D quadratic, minimizer clamped). Conservative margin 1e-3.
            if (valid) {
                const float a_ = pA_, b_ = pB_, c_ = pC_;
                const float dx0 = tx0 - pmx, dx1 = tx1 - pmx;
                const float dy0 = ty0 - pmy, dy1 = ty1 - pmy;
                float smin;
                if (dx0 <= 0.f && 0.f <= dx1 && dy0 <= 0.f && 0.f <= dy1) {
                    smin = 0.f;
                } else {
                    const float ra = 1.0f / a_, rc = 1.0f / c_;
                    // edge x = dx0
                    float yy = fminf(fmaxf(-b_ * dx0 * rc, dy0), dy1);
                    float s0 = 0.5f*a_*dx0*dx0 + b_*dx0*yy + 0.5f*c_*yy*yy;
                    // edge x = dx1
                    yy = fminf(fmaxf(-b_ * dx1 * rc, dy0), dy1);
                    float s1 = 0.5f*a_*dx1*dx1 + b_*dx1*yy + 0.5f*c_*yy*yy;
                    // edge y = dy0
                    float xx = fminf(fmaxf(-b_ * dy0 * ra, dx0), dx1);
                    float s2 = 0.5f*a_*xx*xx + b_*xx*dy0 + 0.5f*c_*dy0*dy0;
                    // edge y = dy1
                    xx = fminf(fmaxf(-b_ * dy1 * ra, dx0), dx1);
                    float s3 = 0.5f*a_*xx*xx + b_*xx*dy1 + 0.5f*c_*dy1*dy1;
                    smin = fminf(fminf(s0, s1), fminf(s2, s3));
                }
                // op*exp(-smin) >= 1/255  <=>  smin <= log(255*op)
                hit = (smin <= __logf(pop * 255.0f) + 1e-3f);
            }
        }
        phit = hit;
        mreg = __ballot(hit);
        if ((lt & 63) == 0) scnt[wave] = __popcll(mreg);
    }
    __syncthreads();

    if (lt == 0) {
        int acc = 0;
        for (int c = 0; c < nchunks; ++c) { sbase[c] = acc; acc += scnt[c]; }
        sbase[nchunks] = acc;
    }
    __syncthreads();
    const int k = sbase[nchunks];

    // compact survivor z's (original-index order == stable key order)
    int pslot = -1;
    if (lt < MAXP && phit) {
        pslot = sbase[wave] + __popcll(mreg & ((1ull << (lt & 63)) - 1ull));
        zc[pslot] = pz;
    }
    if (lt < 4) zc[k + lt] = INFINITY;
    __syncthreads();

    // stable rank-sort of survivors; scatter params from registers
    if (pslot >= 0) {
        const float za = pz;
        const int sa = pslot;
        int rank = 0;
        const float4* z4 = (const float4*)zc;
        const int k4 = (k + 3) >> 2;
        for (int j4 = 0; j4 < k4; ++j4) {
            const float4 v = z4[j4];
            const int j = j4 << 2;
            rank += (v.x < za || (v.x == za && (j+0) < sa));
            rank += (v.y < za || (v.y == za && (j+1) < sa));
            rank += (v.z < za || (v.z == za && (j+2) < sa));
            rank += (v.w < za || (v.w == za && (j+3) < sa));
        }
        spts[rank][0] = make_float4(pmx, pmy, pA_, pB_);
        spts[rank][1] = make_float4(pC_, pop, pcr, pcg);
        spts[rank][2] = make_float4(pcb, 0.f, 0.f, 0.f);
    }
    __syncthreads();

    // ------------- depth-parallel compositing: SEG segments x 256 px ----------
    const int s   = lt >> 8;          // segment 0..3 (front..back)
    const int pix = lt & 255;
    const int col = tx + (pix & 15);
    const int row = ty + (pix >> 4);
    const float px = (float)col + 0.5f;
    const float py = (float)row + 0.5f;

    const int beg = (k * s) >> 2;             // SEG == 4
    const int end = (k * (s + 1)) >> 2;

    float T = 1.0f, r_ = 0.f, g_ = 0.f, b_ = 0.f;
    for (int base = beg; base < end; base += 8) {
        const int lim = (base + 8 < end) ? base + 8 : end;
        #pragma unroll 8
        for (int i = base; i < lim; ++i) {
            const float4 a4 = spts[i][0];        // mx, my, cA, cB
            const float4 b4 = spts[i][1];        // cC, op, cr, cg
            const float  cbv = spts[i][2].x;     // cb

            const float dx = px - a4.x;
            const float dy = py - a4.y;
            const float sigma = 0.5f * (a4.z*dx*dx + b4.x*dy*dy) + a4.w*dx*dy;
            float al = b4.y * __expf(-sigma);
            al = fminf(al, 0.999f);
            const bool keep = (sigma >= 0.0f) && (al >= (1.0f/255.0f));
            al = keep ? al : 0.0f;

            const float w = T * al;
            r_ += w * b4.z;
            g_ += w * b4.w;
            b_ += w * cbv;
            T = __builtin_fmaf(-al, T, T);       // T *= (1 - al), 1 slot
        }
        if (!__any(T > 1e-4f)) break;    // segment tail scaled by <=1: err <= 1e-4
    }

    if (s > 0) comb[s - 1][pix] = make_float4(r_, g_, b_, T);
    __syncthreads();

    if (s == 0) {
        const float4 f1 = comb[0][pix];
        const float4 f2 = comb[1][pix];
        const float4 f3 = comb[2][pix];
        // fold back-to-front: C = C0 + T0*(C1 + T1*(C2 + T2*C3)); T = prod
        float rr = r_ + T * (f1.x + f1.w * (f2.x + f2.w * f3.x));
        float gg = g_ + T * (f1.y + f1.w * (f2.y + f2.w * f3.y));
        float bb = b_ + T * (f1.z + f1.w * (f2.z + f2.w * f3.z));
        const float Tt = T * f1.w * f2.w * f3.w;
        rr += Tt * BGc; gg += Tt * BGc; bb += Tt * BGc;

        const int opix = row * W + col;
        if (opix < npix) {
            out[3*opix + 0] = rr;
            out[3*opix + 1] = gg;
            out[3*opix + 2] = bb;
            out[3*npix + opix] = 1.0f - Tt;
        }
    }
}

extern "C" void kernel_launch(void* const* d_in, const int* in_sizes, int n_in,
                              void* d_out, int out_size, void* d_ws, size_t ws_size,
                              hipStream_t stream) {
    const float* cam    = (const float*)d_in[0];
    const float* means  = (const float*)d_in[1];
    const float* quats  = (const float*)d_in[2];
    const float* scales = (const float*)d_in[3];
    const float* opacs  = (const float*)d_in[4];
    const float* sh0    = (const float*)d_in[5];
    // d_in[6] = shN (unused by the reference render)
    const int* img_w = (const int*)d_in[8];

    const int n = in_sizes[4];            // N_PTS (== 512 for this problem)
    const int npix = out_size / 4;        // 3 color + 1 alpha per pixel

    const int blocks = npix / 256;        // one 16x16 tile per block
    gs_fused<<<blocks, 1024, 0, stream>>>(cam, means, quats, scales, opacs, sh0,
                                          img_w, (float*)d_out, n, npix);
}